// Round 5
// baseline (84.676 us; speedup 1.0000x reference)
//
#include <hip/hip_runtime.h>

// KNN (k=16) within batch-diagonal blocks + neighbor-feature mean-pool.
// N = 16384 points, 8 batches of 2048 (contiguous), FEAT = 16.
//
// R4 -> R5:
//  * Seed phase: per point, thr = max over 16 lanes of (min d2 over 32
//    disjoint sample candidates). Max of 16 distinct candidate distances is
//    provably >= the final 16th-best => always a VALID pruning threshold
//    (quality ~q0.09). Kills the per-wave flood + first-flush redundancy.
//  * thr is static after seeding: scan test is 5 VALU/candidate:
//    dot >= qs*0.5 + C, C = (x2s - thr)*0.5 - 0.03 (margin >> rounding
//    error => strictly more permissive than exact d2<=thr; extra appends
//    are filtered exactly by the u64-key flush/merge). Exact d2 recomputed
//    on the (rare) append path only.
//  * Flush/merge/gather machinery unchanged from R4 (passed, absmax 2.4e-4).

typedef unsigned long long u64;
typedef unsigned int u32;

#define KNN_K 16
#define FEAT 16
#define NSEG 16                  // waves per block
#define THREADS (NSEG * 64)
#define INF_KEY 0xFFFFFFFFFFFFFFFFull
#define FLUSH_AT 12              // flush when cnt > 12 (checked every 4 iters)
#define SEED_PER_LANE 32         // sample candidates per lane in seed phase

__global__ void knn_prep(const float* __restrict__ y, float4* __restrict__ yp, int m)
{
    const int j = blockIdx.x * 256 + (int)threadIdx.x;
    if (j < m) {
        const float a0 = y[(size_t)j * 3 + 0];
        const float a1 = y[(size_t)j * 3 + 1];
        const float a2 = y[(size_t)j * 3 + 2];
        const float s  = __fadd_rn(__fadd_rn(__fmul_rn(a0, a0), __fmul_rn(a1, a1)),
                                   __fmul_rn(a2, a2));
        yp[j] = make_float4(a0, a1, a2, s);
    }
}

// Swizzled slot within a lane's 16-u64 LDS region (bank spread).
__device__ __forceinline__ int sw16(int t, int lane) { return t ^ (lane & 15); }

// Monotonic f32 -> u32 (order-preserving incl. negatives).
__device__ __forceinline__ u32 mono(float f) {
    const u32 b = __float_as_uint(f);
    return b ^ (((u32)(((int)b) >> 31)) | 0x80000000u);
}

__device__ __forceinline__ void flush16(u64 (&inc)[16], u64* buf, int lane,
                                        int& cnt, bool& first)
{
    u64 v[16];
#pragma unroll
    for (int t = 0; t < 16; ++t) v[t] = buf[sw16(t, lane)];

    // Bitonic sort-16, ascending (static indexing, wide independent CEs).
#pragma unroll
    for (int k = 2; k <= 16; k <<= 1) {
#pragma unroll
        for (int j = k >> 1; j > 0; j >>= 1) {
#pragma unroll
            for (int a = 0; a < 16; ++a) {
                const int b = a ^ j;
                if (b > a) {
                    const bool up = (a & k) == 0;
                    const u64 va = v[a], vb = v[b];
                    const bool sw = up ? (vb < va) : (va < vb);
                    v[a] = sw ? vb : va;
                    v[b] = sw ? va : vb;
                }
            }
        }
    }

    if (first) {
#pragma unroll
        for (int t = 0; t < 16; ++t) inc[t] = v[t];
    } else {
        // Half-cleaner vs sorted incumbent -> low 16 (bitonic), then clean.
        u64 m[16];
#pragma unroll
        for (int t = 0; t < 16; ++t) {
            const u64 a = inc[t], b = v[15 - t];
            m[t] = (a < b) ? a : b;
        }
#pragma unroll
        for (int j = 8; j > 0; j >>= 1) {
#pragma unroll
            for (int a = 0; a < 16; ++a) {
                const int b = a ^ j;
                if (b > a) {
                    const u64 va = m[a], vb = m[b];
                    const bool sw = vb < va;
                    m[a] = sw ? vb : va;
                    m[b] = sw ? va : vb;
                }
            }
        }
#pragma unroll
        for (int t = 0; t < 16; ++t) inc[t] = m[t];
    }
    first = false;

#pragma unroll
    for (int t = 0; t < 16; ++t) buf[sw16(t, lane)] = INF_KEY;
    cnt = 0;
}

__global__ __launch_bounds__(THREADS, 4) void knn_main(
    const float* __restrict__ x, const float4* __restrict__ yp,
    const float* __restrict__ y, const float* __restrict__ feat,
    const int* __restrict__ x_batch, float* __restrict__ out,
    int n, int per, int packed)
{
    __shared__ u64 pu[NSEG * 64 * 16];     // 128 KiB candidate/partial lists
    __shared__ u32 idx_s[64 * KNN_K];      // 4 KiB winning indices
    __shared__ float thr_s[64];            // seeded per-point thresholds (f32)

    const int lane  = (int)threadIdx.x & 63;
    const int wv    = __builtin_amdgcn_readfirstlane((int)(threadIdx.x >> 6));
    const int pbase = blockIdx.x * 64;

    const int b     = x_batch[pbase];      // uniform across block
    const int ybase = b * per;

    u64* buf = &pu[(wv * 64 + lane) * 16];
#pragma unroll
    for (int t = 0; t < 16; ++t) buf[sw16(t, lane)] = INF_KEY;

    // ---- Seed phase: wave wv seeds points 4*wv .. 4*wv+3 (one per 16-lane
    // group). Lane samples 32 disjoint candidates; thr = max of lane-mins.
    {
        const int g    = lane >> 4;                  // group 0..3
        const int l16  = lane & 15;
        const int ps   = pbase + wv * 4 + g;         // seed point
        const float sx0 = x[(size_t)ps * 3 + 0];
        const float sx1 = x[(size_t)ps * 3 + 1];
        const float sx2 = x[(size_t)ps * 3 + 2];
        const float sx2s = __fadd_rn(__fadd_rn(__fmul_rn(sx0, sx0), __fmul_rn(sx1, sx1)),
                                     __fmul_rn(sx2, sx2));
        float md = __builtin_inff();
        const int jb = ybase + l16 * SEED_PER_LANE;
#pragma unroll 4
        for (int t = 0; t < SEED_PER_LANE; ++t) {
            float q0, q1, q2, qs;
            if (packed) {
                const float4 q = yp[jb + t];
                q0 = q.x; q1 = q.y; q2 = q.z; qs = q.w;
            } else {
                q0 = y[(size_t)(jb + t) * 3 + 0];
                q1 = y[(size_t)(jb + t) * 3 + 1];
                q2 = y[(size_t)(jb + t) * 3 + 2];
                qs = __fadd_rn(__fadd_rn(__fmul_rn(q0, q0), __fmul_rn(q1, q1)),
                               __fmul_rn(q2, q2));
            }
            float dot = __fmaf_rn(sx0, q0, 0.0f);
            dot = __fmaf_rn(sx1, q1, dot);
            dot = __fmaf_rn(sx2, q2, dot);
            const float d2 = __fsub_rn(__fadd_rn(sx2s, qs), __fmul_rn(2.0f, dot));
            md = fminf(md, d2);
        }
        // max over the 16 lane-mins (shfl_xor masks < 16 stay in-group)
#pragma unroll
        for (int mask = 1; mask <= 8; mask <<= 1)
            md = fmaxf(md, __shfl_xor(md, mask));
        if (l16 == 0) thr_s[wv * 4 + g] = md;
    }
    __syncthreads();

    // ---- Scan phase: lane <-> point, wave <-> 128-candidate segment.
    const int i = pbase + lane;
    const float px0 = x[(size_t)i * 3 + 0];
    const float px1 = x[(size_t)i * 3 + 1];
    const float px2 = x[(size_t)i * 3 + 2];
    const float x2s = __fadd_rn(__fadd_rn(__fmul_rn(px0, px0), __fmul_rn(px1, px1)),
                                __fmul_rn(px2, px2));

    const float thrf = thr_s[lane];
    // keep iff dot >= qs*0.5 + C  (conservative: margin 0.03 >> rounding
    // error of the rearrangement => never drops a true candidate).
    const float C = (x2s - thrf) * 0.5f - 0.03f;

    u64 inc[16];
#pragma unroll
    for (int t = 0; t < 16; ++t) inc[t] = INF_KEY;
    bool first = true;
    int  cnt   = 0;

    const int seg_len = per / NSEG;        // 128
    const int jbeg    = ybase + wv * seg_len;

    for (int j4 = 0; j4 < seg_len; j4 += 4) {
#pragma unroll
        for (int u = 0; u < 4; ++u) {
            const int j = jbeg + j4 + u;   // wave-uniform
            float q0, q1, q2, qs;
            if (packed) {
                const float4 q = yp[j];
                q0 = q.x; q1 = q.y; q2 = q.z; qs = q.w;
            } else {
                q0 = y[(size_t)j * 3 + 0];
                q1 = y[(size_t)j * 3 + 1];
                q2 = y[(size_t)j * 3 + 2];
                qs = __fadd_rn(__fadd_rn(__fmul_rn(q0, q0), __fmul_rn(q1, q1)),
                               __fmul_rn(q2, q2));
            }
            float dot = __fmaf_rn(px0, q0, 0.0f);
            dot = __fmaf_rn(px1, q1, dot);
            dot = __fmaf_rn(px2, q2, dot);
            const float test = __fmaf_rn(qs, 0.5f, C);
            if (dot >= test) {
                // Exact d2 (reference arithmetic) only on the append path.
                const float d2 = __fsub_rn(__fadd_rn(x2s, qs), __fmul_rn(2.0f, dot));
                buf[sw16(cnt, lane)] = ((u64)mono(d2) << 32) | (u32)j;
                cnt++;
            }
        }
        if (__any(cnt > FLUSH_AT)) flush16(inc, buf, lane, cnt, first);
    }
    if (__any(cnt > 0)) flush16(inc, buf, lane, cnt, first);

    // Publish sorted per-segment top-16 (reuse buffer region).
#pragma unroll
    for (int t = 0; t < 16; ++t) buf[sw16(t, lane)] = inc[t];
    __syncthreads();

    // Index-only 16-way merge: lanes 0..3, point p = wv*4 + lane.
    if (lane < 4) {
        const int p = wv * 4 + lane;
        int h[NSEG];
#pragma unroll
        for (int s = 0; s < NSEG; ++s) h[s] = 0;
#pragma unroll
        for (int r = 0; r < KNN_K; ++r) {
            u64 best = INF_KEY;
            int bs = 0;
#pragma unroll
            for (int s = 0; s < NSEG; ++s) {
                const u64 d = pu[(s * 64 + p) * 16 + sw16(h[s], p)];
                if (d < best) { best = d; bs = s; }   // keys unique
            }
#pragma unroll
            for (int s = 0; s < NSEG; ++s)
                if (s == bs) h[s]++;
            idx_s[p * KNN_K + r] = (u32)best;         // low word = y index
        }
    }
    // Same-wave producer/consumer (in-order DS pipe; no barrier needed).

    // Full-wave gather: lane = (point gp, rank gr); butterfly-sum over ranks.
    const int gp = lane >> 4;              // 0..3 (point within wave's quad)
    const int gr = lane & 15;              // rank
    const int p_out = wv * 4 + gp;
    const int gidx = (int)idx_s[p_out * KNN_K + gr];

    const float4* fp = (const float4*)feat + (size_t)gidx * 4;
    const float4 f0 = fp[0], f1 = fp[1], f2 = fp[2], f3 = fp[3];
    float f[FEAT] = { f0.x, f0.y, f0.z, f0.w, f1.x, f1.y, f1.z, f1.w,
                      f2.x, f2.y, f2.z, f2.w, f3.x, f3.y, f3.z, f3.w };
#pragma unroll
    for (int mask = 1; mask <= 8; mask <<= 1) {
#pragma unroll
        for (int c = 0; c < FEAT; ++c)
            f[c] = __fadd_rn(f[c], __shfl_xor(f[c], mask));
    }
    if (gr < 4) {
        float4* o4 = (float4*)out + (size_t)(pbase + p_out) * 4;
        o4[gr] = make_float4(__fmul_rn(f[gr * 4 + 0], 0.0625f),
                             __fmul_rn(f[gr * 4 + 1], 0.0625f),
                             __fmul_rn(f[gr * 4 + 2], 0.0625f),
                             __fmul_rn(f[gr * 4 + 3], 0.0625f));
    }
}

extern "C" void kernel_launch(void* const* d_in, const int* in_sizes, int n_in,
                              void* d_out, int out_size, void* d_ws, size_t ws_size,
                              hipStream_t stream) {
    const float* x       = (const float*)d_in[0];
    const float* y       = (const float*)d_in[1];
    const float* feat    = (const float*)d_in[2];
    const int*   x_batch = (const int*)d_in[3];

    const int n   = in_sizes[0] / 3;   // 16384 query points
    const int m   = in_sizes[1] / 3;   // 16384 y points
    const int per = m / 8;             // 2048 per batch (N_BATCHES = 8)

    float* out = (float*)d_out;

    const size_t need = (size_t)m * sizeof(float4);
    const int packed = (ws_size >= need) ? 1 : 0;
    float4* yp = (float4*)d_ws;

    if (packed)
        knn_prep<<<(m + 255) / 256, 256, 0, stream>>>(y, yp, m);

    const int blocks = n / 64;         // 256
    knn_main<<<blocks, THREADS, 0, stream>>>(x, yp, y, feat, x_batch, out,
                                             n, per, packed);
}